// Round 10
// baseline (3374.655 us; speedup 1.0000x reference)
//
#include <hip/hip_runtime.h>

#define B_ 64
#define T_ 512
#define E_ 512
#define H_ 1024
#define C_ 20
#define RING 16
#define BH (B_ * H_)

typedef __attribute__((ext_vector_type(8))) _Float16 f16x8;
typedef __attribute__((ext_vector_type(4))) float f32x4;
typedef __attribute__((ext_vector_type(4))) unsigned int u32x4;
typedef unsigned long long u64;

__device__ __forceinline__ void st_agent_u64(u64* p, u64 v){
  __hip_atomic_store(p, v, __ATOMIC_RELAXED, __HIP_MEMORY_SCOPE_AGENT);
}
__device__ __forceinline__ u64 ld_agent_u64(const u64* p){
  return __hip_atomic_load(p, __ATOMIC_RELAXED, __HIP_MEMORY_SCOPE_AGENT);
}
// Coherent 16B load (bypasses L1/L2, reads the device-coherent point).
// Caller must s_waitcnt vmcnt(0) + sched_barrier(0) before consuming.
__device__ __forceinline__ u32x4 ld_b128_cohere(const void* p){
  u32x4 r;
  asm volatile("global_load_dwordx4 %0, %1, off sc0 sc1"
               : "=v"(r) : "v"(p) : "memory");
  return r;
}

// ---------------------------------------------------------------------------
// Prep: W_hh/W_ih -> fp16, init h-ring (slot0 = h0 = zeros, slots 1..15 =
// 0xFFFF sentinel = fp16 NaN, never produced by tanh) and the probe ring.
// Rings MUST be re-inited every launch (ws not re-poisoned between replays).
// ---------------------------------------------------------------------------
__global__ void prep_kernel(const float* __restrict__ wih,
                            const float* __restrict__ whh,
                            _Float16* __restrict__ whhF,
                            _Float16* __restrict__ wihF,
                            short* __restrict__ hring,
                            u64* __restrict__ pring)
{
  const long NH = (long)H_ * H_;
  const long NI = (long)H_ * E_;
  const long NR = (long)RING * BH;
  const long NP = RING * 128;               // probe ring (u64 granules)
  const long TOT = NH + NI + NR + NP;
  long i = (long)blockIdx.x * blockDim.x + threadIdx.x;
  const long stride = (long)gridDim.x * blockDim.x;
  for (; i < TOT; i += stride){
    if (i < NH){
      whhF[i] = (_Float16)whh[i];
    } else if (i < NH + NI){
      long j = i - NH;
      wihF[j] = (_Float16)wih[j];
    } else if (i < NH + NI + NR){
      long j = i - NH - NI;
      hring[j] = (j < BH) ? (short)0 : (short)0xFFFF;
    } else {
      long j = i - NH - NI - NR;
      pring[j] = (j < 128) ? 0ull : 0xFFFFFFFFFFFFFFFFull;
    }
  }
}

// ---------------------------------------------------------------------------
// probe_scan (DIAGNOSTIC): pure-exchange skeleton, identical topology and
// protocol to rnn_scan (128 blocks, fan-in 32 within bg, 16-slot sentinel
// ring, re-sentinel t+8, 512 steps) with ZERO compute. Its dur_us is the
// fabric floor: publish -> coherent-point visibility -> detect, per step.
// Hardened: all 64 lanes load (no divergent asm; lanes l and l+32 read the
// same granule); spin budget aborts the whole scan on overflow so a protocol
// flaw can only waste bounded time, never wedge the queue.
// ---------------------------------------------------------------------------
__global__ __launch_bounds__(64, 1) void probe_scan(u64* __restrict__ ring)
{
  const int lane = threadIdx.x;
  const int bg   = blockIdx.x >> 5;
  const long self = (long)blockIdx.x;          // own granule index

  for (int t = 0; t < T_; ++t){
    const u64* rb = ring + (long)(t & (RING - 1)) * 128 + bg * 32 + (lane & 31);
    int spins = 0;
    bool bad;
    do {
      u64 v = ld_agent_u64(rb);
      bad = (((unsigned)v & 0xFFFFu) == 0xFFFFu);
    } while (__any(bad) && ++spins < 65536);
    if (spins >= 65536) return;                // wedge guard — abandon probe
    if (lane == 0 && t < T_ - 1){
      st_agent_u64(ring + (long)((t + 1) & (RING - 1)) * 128 + self,
                   0x3C003C003C003C00ull);
      if (t + 8 < T_)
        st_agent_u64(ring + (long)((t + 8) & (RING - 1)) * 128 + self,
                     0xFFFFFFFFFFFFFFFFull);
    }
  }
}

// ---------------------------------------------------------------------------
// xp_gemm: xp[t][b][h] = x[b][t][:] @ W_ih[h][:] + b_ih[h] + b_hh[h], fp16,
// stored PRE-SWIZZLED in MFMA C-fragment order so the scan reads one u64 per
// lane per col-chunk.
// ---------------------------------------------------------------------------
__global__ __launch_bounds__(256, 1) void xp_gemm(
    const float* __restrict__ x, const _Float16* __restrict__ wihF,
    const float* __restrict__ bih, const float* __restrict__ bhh,
    u64* __restrict__ xp)
{
  const int lane = threadIdx.x & 63;
  const int wv   = threadIdx.x >> 6;       // 0..3 -> col quarter
  const int bg   = blockIdx.x & 3;
  const int tb   = (blockIdx.x >> 2) * 4;  // 4 timesteps per block
  const int r16  = lane & 15;
  const int k8   = (lane >> 4) * 8;

  const int brow = bg * 16 + r16;

  f32x4 acc[4][16];
  #pragma unroll
  for (int t = 0; t < 4; t++)
    #pragma unroll
    for (int c = 0; c < 16; c++) acc[t][c] = { 0.f, 0.f, 0.f, 0.f };

  for (int kc = 0; kc < 16; kc++){
    f16x8 a[4];
    #pragma unroll
    for (int t = 0; t < 4; t++){
      const float* xp8 = x + ((long)brow * T_ + tb + t) * E_ + kc * 32 + k8;
      float4 f0 = *(const float4*)xp8;
      float4 f1 = *(const float4*)(xp8 + 4);
      f16x8 v;
      v[0]=(_Float16)f0.x; v[1]=(_Float16)f0.y; v[2]=(_Float16)f0.z; v[3]=(_Float16)f0.w;
      v[4]=(_Float16)f1.x; v[5]=(_Float16)f1.y; v[6]=(_Float16)f1.z; v[7]=(_Float16)f1.w;
      a[t] = v;
    }
    #pragma unroll
    for (int c = 0; c < 16; c++){
      f16x8 b = *(const f16x8*)(wihF + (long)(wv * 256 + c * 16 + r16) * E_ + kc * 32 + k8);
      #pragma unroll
      for (int t = 0; t < 4; t++)
        acc[t][c] = __builtin_amdgcn_mfma_f32_16x16x32_f16(a[t], b, acc[t][c], 0, 0, 0);
    }
  }
  #pragma unroll
  for (int c = 0; c < 16; c++){
    int col = wv * 256 + c * 16 + r16;
    float bs = bih[col] + bhh[col];
    int cc = wv * 16 + c;
    #pragma unroll
    for (int t = 0; t < 4; t++){
      union { _Float16 h[4]; u64 q; } pu;
      #pragma unroll
      for (int j = 0; j < 4; j++) pu.h[j] = (_Float16)(acc[t][c][j] + bs);
      xp[(((long)(tb + t) * 64 + cc) * 4 + bg) * 64 + lane] = pu.q;
    }
  }
}

// ---------------------------------------------------------------------------
// Persistent scan (EXACT R8 structure — known-pass baseline). 128 blocks x
// 64 threads (one wave each, zero barriers). Wave (bg,cg) owns [16 batch x
// 32 cols], FULL K=1024: 64 recurrent MFMAs, W_hh pinned in 256 VGPRs.
// Input projection precomputed (xp_gemm); per step the wave reads 2x8B xp
// granules, prefetched one step ahead. 16-slot sentinel ring exchange.
// ---------------------------------------------------------------------------
__global__ __launch_bounds__(64, 1) void rnn_scan(
    const u64* __restrict__ xp, const _Float16* __restrict__ whhF,
    _Float16* __restrict__ hring, float* __restrict__ hT)
{
  const int lane = threadIdx.x;       // 0..63
  const int bg   = blockIdx.x >> 5;   // batch group 0..3
  const int cg   = blockIdx.x & 31;   // col group 0..31 (32 cols each)
  const int r16  = lane & 15;
  const int k8   = (lane >> 4) * 8;

  __shared__ float tile[16][36];      // 16 x 32 f32 transpose buffer (+4 pad)

  const int hrow = bg * 16 + r16;     // batch row (A-frag row)

  // --- pinned W_hh fragments: 2 col-chunks x 32 K-chunks ---
  f16x8 whA[32], whB[32];
  #pragma unroll
  for (int c = 0; c < 32; c++){
    whA[c] = *(const f16x8*)(whhF + (long)(cg * 32 + r16) * H_ + c * 32 + k8);
    whB[c] = *(const f16x8*)(whhF + (long)(cg * 32 + 16 + r16) * H_ + c * 32 + k8);
  }
  #pragma unroll
  for (int c = 0; c < 32; c++) asm volatile("" : "+v"(whA[c]), "+v"(whB[c]));

  const long haOff = (long)hrow * H_ + k8;          // + c*32 + slot*BH
  const int  prow  = lane >> 2;                     // publish row 0..15
  const int  pc0   = (lane & 3) * 4;                // publish col0 (of 32)
  const long pub0  = (long)(bg * 16 + prow) * H_ + cg * 32 + pc0;
  const long pub1  = pub0 + 16;
  const long xpb0  = ((long)(cg * 2 + 0) * 4 + bg) * 64 + lane;
  const long xpb1  = ((long)(cg * 2 + 1) * 4 + bg) * 64 + lane;

  // prologue: xp(0)
  u64 xc0 = xp[xpb0], xc1 = xp[xpb1];

  for (int t = 0; t < T_; ++t){
    // ---- prefetch xp(t+1) (plain cached loads; consumed next iteration) ----
    u64 xn0 = 0, xn1 = 0;
    if (t + 1 < T_){
      xn0 = xp[(long)(t + 1) * 16384 + xpb0];
      xn1 = xp[(long)(t + 1) * 16384 + xpb1];
    }

    // ---- acc init from xp(t) ----
    f32x4 accA, accB;
    {
      const _Float16* p0 = (const _Float16*)&xc0;
      const _Float16* p1 = (const _Float16*)&xc1;
      #pragma unroll
      for (int j = 0; j < 4; j++){ accA[j] = (float)p0[j]; accB[j] = (float)p1[j]; }
    }

    // ---- poll h(t): 32 x 16B coherent loads, arrival-order fused MFMAs ----
    const _Float16* hb = hring + (long)(t & (RING - 1)) * BH + haOff;
    u32x4 q[32];
    #pragma unroll
    for (int c = 0; c < 32; c++) q[c] = ld_b128_cohere(hb + c * 32);
    asm volatile("s_waitcnt vmcnt(0)" ::: "memory");
    __builtin_amdgcn_sched_barrier(0);

    unsigned need = 0xFFFFFFFFu;
    while (true){
      #pragma unroll
      for (int c = 0; c < 32; c++){
        if (need & (1u << c)){
          bool bad = ((q[c][0] & 0xFFFFu) == 0xFFFFu) ||
                     ((q[c][2] & 0xFFFFu) == 0xFFFFu);
          if (!__any(bad)){
            union { u32x4 u; f16x8 v; } hu; hu.u = q[c];
            accA = __builtin_amdgcn_mfma_f32_16x16x32_f16(hu.v, whA[c], accA, 0, 0, 0);
            accB = __builtin_amdgcn_mfma_f32_16x16x32_f16(hu.v, whB[c], accB, 0, 0, 0);
            need &= ~(1u << c);
          }
        }
      }
      if (!need) break;
      #pragma unroll
      for (int c = 0; c < 32; c++)
        if (need & (1u << c)) q[c] = ld_b128_cohere(hb + c * 32);
      asm volatile("s_waitcnt vmcnt(0)" ::: "memory");
      __builtin_amdgcn_sched_barrier(0);
    }

    // ---- tanh ----
    float hv[8];
    #pragma unroll
    for (int j = 0; j < 4; j++){
      float s = accA[j], a = fabsf(s), ex = __expf(-2.f * a);
      hv[j] = copysignf((1.f - ex) / (1.f + ex), s);
    }
    #pragma unroll
    for (int j = 0; j < 4; j++){
      float s = accB[j], a = fabsf(s), ex = __expf(-2.f * a);
      hv[4 + j] = copysignf((1.f - ex) / (1.f + ex), s);
    }

    // ---- in-wave LDS transpose: C-frag (col=r16, row=(lane>>4)*4+j) ----
    #pragma unroll
    for (int j = 0; j < 4; j++){
      tile[(lane >> 4) * 4 + j][r16]      = hv[j];
      tile[(lane >> 4) * 4 + j][16 + r16] = hv[4 + j];
    }
    f32x4 o0 = *(const f32x4*)&tile[prow][pc0];        // compiler orders DS ops
    f32x4 o1 = *(const f32x4*)&tile[prow][pc0 + 16];

    if (t < T_ - 1){
      // ---- publish 2 granules + re-sentinel slot t+8 ----
      union { _Float16 h[4]; u64 q; } g0, g1;
      #pragma unroll
      for (int j = 0; j < 4; j++){ g0.h[j] = (_Float16)o0[j]; g1.h[j] = (_Float16)o1[j]; }
      _Float16* hn = hring + (long)((t + 1) & (RING - 1)) * BH;
      st_agent_u64((u64*)(hn + pub0), g0.q);
      st_agent_u64((u64*)(hn + pub1), g1.q);
      if (t + 8 < T_){
        _Float16* hs = hring + (long)((t + 8) & (RING - 1)) * BH;
        st_agent_u64((u64*)(hs + pub0), 0xFFFFFFFFFFFFFFFFull);
        st_agent_u64((u64*)(hs + pub1), 0xFFFFFFFFFFFFFFFFull);
      }
      xc0 = xn0; xc1 = xn1;
    } else {
      *(float4*)(hT + pub0) = make_float4(o0[0], o0[1], o0[2], o0[3]);
      *(float4*)(hT + pub1) = make_float4(o1[0], o1[1], o1[2], o1[3]);
    }
  }
}

// ---------------------------------------------------------------------------
// Head: y1 = relu(hT @ fc1_w^T + b1);  out = y1 @ fc2_w^T + b2   (all fp32)
// ---------------------------------------------------------------------------
__global__ void fc1_kernel(const float* __restrict__ hT, const float* __restrict__ w1,
                           const float* __restrict__ b1, float* __restrict__ y1)
{
  int o = blockIdx.x * 256 + threadIdx.x;     // 0..65535
  int b = o >> 10, j = o & 1023;
  const float4* hp = (const float4*)(hT + (long)b * H_);
  const float4* wp = (const float4*)(w1 + (long)j * H_);
  float s = 0.f;
  #pragma unroll 4
  for (int k = 0; k < H_ / 4; k++){
    float4 hv = hp[k], wv = wp[k];
    s += hv.x * wv.x + hv.y * wv.y + hv.z * wv.z + hv.w * wv.w;
  }
  s += b1[j];
  y1[o] = s > 0.f ? s : 0.f;
}

__global__ void fc2_kernel(const float* __restrict__ y1, const float* __restrict__ w2,
                           const float* __restrict__ b2, float* __restrict__ out)
{
  __shared__ float ybuf[H_];
  int b = blockIdx.x;
  for (int k = threadIdx.x; k < H_; k += 256) ybuf[k] = y1[(long)b * H_ + k];
  __syncthreads();
  if (threadIdx.x < C_){
    const float* wp = w2 + (long)threadIdx.x * H_;
    float s = 0.f;
    for (int k = 0; k < H_; k++) s += ybuf[k] * wp[k];
    out[b * C_ + threadIdx.x] = s + b2[threadIdx.x];
  }
}

// ---------------------------------------------------------------------------
extern "C" void kernel_launch(void* const* d_in, const int* in_sizes, int n_in,
                              void* d_out, int out_size, void* d_ws, size_t ws_size,
                              hipStream_t stream)
{
  const float* x   = (const float*)d_in[0];
  const float* wih = (const float*)d_in[1];
  const float* whh = (const float*)d_in[2];
  const float* bih = (const float*)d_in[3];
  const float* bhh = (const float*)d_in[4];
  const float* w1  = (const float*)d_in[5];
  const float* b1  = (const float*)d_in[6];
  const float* w2  = (const float*)d_in[7];
  const float* b2  = (const float*)d_in[8];
  float* out = (float*)d_out;

  char* ws = (char*)d_ws;
  size_t off = 0;
  auto carve = [&](size_t bytes) -> char* {
    char* p = ws + off; off += (bytes + 255) & ~(size_t)255; return p;
  };
  // R8-identical layout for the first six buffers; pring appended last.
  _Float16* whhF  = (_Float16*)carve((size_t)H_ * H_ * 2);
  _Float16* wihF  = (_Float16*)carve((size_t)H_ * E_ * 2);
  _Float16* hring = (_Float16*)carve((size_t)RING * BH * 2);
  float*    hT    = (float*)carve((size_t)B_ * H_ * 4);
  float*    y1    = (float*)carve((size_t)B_ * H_ * 4);
  u64*      xp    = (u64*)carve((size_t)T_ * 64 * 4 * 64 * 8);   // 64 MB
  u64*      pring = (u64*)carve((size_t)RING * 128 * 8);

  prep_kernel<<<1024, 256, 0, stream>>>(wih, whh, whhF, wihF,
                                        (short*)hring, pring);
  probe_scan<<<128, 64, 0, stream>>>(pring);
  xp_gemm<<<512, 256, 0, stream>>>(x, wihF, bih, bhh, xp);
  rnn_scan<<<128, 64, 0, stream>>>(xp, whhF, hring, hT);
  fc1_kernel<<<256, 256, 0, stream>>>(hT, w1, b1, y1);
  fc2_kernel<<<64, 256, 0, stream>>>(y1, w2, b2, out);
}

// Round 11
// 2122.234 us; speedup vs baseline: 1.5901x; 1.5901x over previous
//
#include <hip/hip_runtime.h>

#define B_ 64
#define T_ 512
#define E_ 512
#define H_ 1024
#define C_ 20
#define RING 16
#define BH (B_ * H_)

typedef __attribute__((ext_vector_type(8))) _Float16 f16x8;
typedef __attribute__((ext_vector_type(4))) float f32x4;
typedef __attribute__((ext_vector_type(4))) unsigned int u32x4;
typedef unsigned long long u64;

__device__ __forceinline__ void st_agent_u64(u64* p, u64 v){
  __hip_atomic_store(p, v, __ATOMIC_RELAXED, __HIP_MEMORY_SCOPE_AGENT);
}
// Coherent 16B load (bypasses L1/L2, reads the device-coherent point).
// Caller must s_waitcnt vmcnt(0) + sched_barrier(0) before consuming.
__device__ __forceinline__ u32x4 ld_b128_cohere(const void* p){
  u32x4 r;
  asm volatile("global_load_dwordx4 %0, %1, off sc0 sc1"
               : "=v"(r) : "v"(p) : "memory");
  return r;
}

// ---------------------------------------------------------------------------
// Prep: W_hh/W_ih -> fp16, init h-ring (slot0 = h0 = zeros, slots 1..15 =
// 0xFFFF sentinel = fp16 NaN, never produced by tanh). Ring MUST be re-inited
// every launch (ws not re-poisoned between graph replays).
// ---------------------------------------------------------------------------
__global__ void prep_kernel(const float* __restrict__ wih,
                            const float* __restrict__ whh,
                            _Float16* __restrict__ whhF,
                            _Float16* __restrict__ wihF,
                            short* __restrict__ hring)
{
  const long NH = (long)H_ * H_;
  const long NI = (long)H_ * E_;
  const long NR = (long)RING * BH;
  const long TOT = NH + NI + NR;
  long i = (long)blockIdx.x * blockDim.x + threadIdx.x;
  const long stride = (long)gridDim.x * blockDim.x;
  for (; i < TOT; i += stride){
    if (i < NH){
      whhF[i] = (_Float16)whh[i];
    } else if (i < NH + NI){
      long j = i - NH;
      wihF[j] = (_Float16)wih[j];
    } else {
      long j = i - NH - NI;
      hring[j] = (j < BH) ? (short)0 : (short)0xFFFF;
    }
  }
}

// ---------------------------------------------------------------------------
// xp_gemm: xp[t][b][h] = x[b][t][:] @ W_ih[h][:] + b_ih[h] + b_hh[h], fp16,
// stored PLAIN [t][b][h] (the scan adds xp at the reducer stage, which reads
// 8 contiguous fp16 per thread — no swizzle needed).
// ---------------------------------------------------------------------------
__global__ __launch_bounds__(256, 1) void xp_gemm(
    const float* __restrict__ x, const _Float16* __restrict__ wihF,
    const float* __restrict__ bih, const float* __restrict__ bhh,
    _Float16* __restrict__ xp)
{
  const int lane = threadIdx.x & 63;
  const int wv   = threadIdx.x >> 6;       // 0..3 -> col quarter
  const int bg   = blockIdx.x & 3;
  const int tb   = (blockIdx.x >> 2) * 4;  // 4 timesteps per block
  const int r16  = lane & 15;
  const int k8   = (lane >> 4) * 8;

  const int brow = bg * 16 + r16;

  f32x4 acc[4][16];
  #pragma unroll
  for (int t = 0; t < 4; t++)
    #pragma unroll
    for (int c = 0; c < 16; c++) acc[t][c] = { 0.f, 0.f, 0.f, 0.f };

  for (int kc = 0; kc < 16; kc++){
    f16x8 a[4];
    #pragma unroll
    for (int t = 0; t < 4; t++){
      const float* xp8 = x + ((long)brow * T_ + tb + t) * E_ + kc * 32 + k8;
      float4 f0 = *(const float4*)xp8;
      float4 f1 = *(const float4*)(xp8 + 4);
      f16x8 v;
      v[0]=(_Float16)f0.x; v[1]=(_Float16)f0.y; v[2]=(_Float16)f0.z; v[3]=(_Float16)f0.w;
      v[4]=(_Float16)f1.x; v[5]=(_Float16)f1.y; v[6]=(_Float16)f1.z; v[7]=(_Float16)f1.w;
      a[t] = v;
    }
    #pragma unroll
    for (int c = 0; c < 16; c++){
      f16x8 b = *(const f16x8*)(wihF + (long)(wv * 256 + c * 16 + r16) * E_ + kc * 32 + k8);
      #pragma unroll
      for (int t = 0; t < 4; t++)
        acc[t][c] = __builtin_amdgcn_mfma_f32_16x16x32_f16(a[t], b, acc[t][c], 0, 0, 0);
    }
  }
  // C-frag: col = wv*256 + c*16 + (lane&15); row = bg*16 + (lane>>4)*4 + j
  #pragma unroll
  for (int c = 0; c < 16; c++){
    int col = wv * 256 + c * 16 + r16;
    float bs = bih[col] + bhh[col];
    #pragma unroll
    for (int t = 0; t < 4; t++){
      #pragma unroll
      for (int j = 0; j < 4; j++){
        int row = bg * 16 + (lane >> 4) * 4 + j;
        xp[((long)(tb + t)) * BH + (long)row * H_ + col] =
            (_Float16)(acc[t][c][j] + bs);
      }
    }
  }
}

// ---------------------------------------------------------------------------
// Persistent scan v7: 32 blocks (4 bg x 8 cg) x 256 threads (4 waves).
// Block owns output tile [16 batch rows x 128 cols], FULL K=1024 split over
// the 4 waves (256 K each). Wave weights: 128 cols x 256 K fp16 = 64 KB =
// 256 VGPRs, pinned (launch_bounds(256,1) -> 1 wave/SIMD, 512-reg budget).
//
// Why this geometry: wave-level exchange fan-in drops 32 -> 2 (K-chunks 0-3
// come from producer block 2ks, 4-7 from 2ks+1), per-wave poll payload drops
// 32KB -> 8KB (8 x 16B per lane), and the K-reduction is INTRA-block (LDS +
// one lgkm-only barrier, double-buffered by t parity — dataflow gates the
// next step's writes so no WAR race).
//
// Exchange protocol (proven R4-R8): 16-slot sentinel ring, 8B single-copy-
// atomic granules, 0xFFFF fp16-NaN sentinel (tanh never produces it),
// re-sentinel slot t+8 (poll-loop vmcnt(0) drains order its commit before
// any later publish of that slot). Arrival-order fused MFMAs.
// xp added at the reducer stage (plain layout, 16B/thread, prefetched).
// ---------------------------------------------------------------------------
__global__ __launch_bounds__(256, 1) void rnn_scan(
    const _Float16* __restrict__ xp, const _Float16* __restrict__ whhF,
    _Float16* __restrict__ hring, float* __restrict__ hT)
{
  const int tid  = threadIdx.x;
  const int lane = tid & 63;
  const int ks   = tid >> 6;          // wave 0..3 -> K quarter
  const int bg   = blockIdx.x & 3;    // batch group (16 rows)
  const int cg   = blockIdx.x >> 2;   // col group 0..7 (128 cols)
  const int r16  = lane & 15;
  const int kq   = lane >> 4;         // 0..3

  __shared__ float lds[2][4][16][132];   // [buf][wave][row][col(+pad)]

  // --- pinned W_hh fragments: [col-tile ct 0..7][K-chunk c 0..7] ---
  f16x8 wh[8][8];
  #pragma unroll
  for (int ct = 0; ct < 8; ct++)
    #pragma unroll
    for (int c = 0; c < 8; c++)
      wh[ct][c] = *(const f16x8*)(whhF +
          (long)(cg * 128 + ct * 16 + r16) * H_ + ks * 256 + c * 32 + kq * 8);
  #pragma unroll
  for (int ct = 0; ct < 8; ct++)
    #pragma unroll
    for (int c = 0; c < 8; c++)
      asm volatile("" : "+v"(wh[ct][c]));

  // consumer A-frag base: row = bg*16 + r16, K = ks*256 + c*32 + kq*8
  const long haOff = (long)(bg * 16 + r16) * H_ + ks * 256 + kq * 8;
  // reducer/publisher mapping: thread -> (row rr, col-octet rc)
  const int  rr = tid >> 4;           // 0..15
  const int  rc = tid & 15;           // 0..15 (8 cols each)
  const long pubOff = (long)(bg * 16 + rr) * H_ + cg * 128 + rc * 8;

  // xp(0) for this thread's 8 outputs
  f16x8 xpc = *(const f16x8*)(xp + pubOff);

  for (int t = 0; t < T_; ++t){
    // ---- poll h(t): 8 x 16B coherent loads, arrival-order fused MFMAs ----
    const _Float16* hb = hring + (long)(t & (RING - 1)) * BH + haOff;
    u32x4 q[8];
    #pragma unroll
    for (int c = 0; c < 8; c++) q[c] = ld_b128_cohere(hb + c * 32);
    asm volatile("s_waitcnt vmcnt(0)" ::: "memory");
    __builtin_amdgcn_sched_barrier(0);

    f32x4 acc[8];
    #pragma unroll
    for (int ct = 0; ct < 8; ct++) acc[ct] = { 0.f, 0.f, 0.f, 0.f };

    unsigned need = 0xFFu;
    while (true){
      #pragma unroll
      for (int c = 0; c < 8; c++){
        if (need & (1u << c)){
          bool bad = ((q[c][0] & 0xFFFFu) == 0xFFFFu) ||
                     ((q[c][2] & 0xFFFFu) == 0xFFFFu);
          if (!__any(bad)){
            union { u32x4 u; f16x8 v; } hu; hu.u = q[c];
            #pragma unroll
            for (int ct = 0; ct < 8; ct++)
              acc[ct] = __builtin_amdgcn_mfma_f32_16x16x32_f16(hu.v, wh[ct][c], acc[ct], 0, 0, 0);
            need &= ~(1u << c);
          }
        }
      }
      if (!need) break;
      #pragma unroll
      for (int c = 0; c < 8; c++)
        if (need & (1u << c)) q[c] = ld_b128_cohere(hb + c * 32);
      asm volatile("s_waitcnt vmcnt(0)" ::: "memory");
      __builtin_amdgcn_sched_barrier(0);
    }

    // ---- partials to LDS (buffer by parity); lgkm-only barrier ----
    {
      float (*buf)[16][132] = lds[t & 1];
      #pragma unroll
      for (int ct = 0; ct < 8; ct++)
        #pragma unroll
        for (int j = 0; j < 4; j++)
          buf[ks][kq * 4 + j][ct * 16 + r16] = acc[ct][j];
    }
    asm volatile("s_waitcnt lgkmcnt(0)\n\ts_barrier" ::: "memory");

    // ---- xp prefetch for t+1 (plain cached load; consumed next iter after
    //      ~a full step of flight; placed after the poll so the round-0
    //      vmcnt(0) of THIS step never waits on it) ----
    f16x8 xpn;
    if (t + 1 < T_)
      xpn = *(const f16x8*)(xp + (long)(t + 1) * BH + pubOff);

    // ---- reduce 4 waves' partials + xp, tanh, publish ----
    {
      const float (*buf)[16][132] = lds[t & 1];
      f32x4 s0 = *(const f32x4*)&buf[0][rr][rc * 8];
      f32x4 s1 = *(const f32x4*)&buf[0][rr][rc * 8 + 4];
      #pragma unroll
      for (int w = 1; w < 4; w++){
        s0 += *(const f32x4*)&buf[w][rr][rc * 8];
        s1 += *(const f32x4*)&buf[w][rr][rc * 8 + 4];
      }
      float hv[8];
      #pragma unroll
      for (int j = 0; j < 4; j++){
        float s = s0[j] + (float)xpc[j];
        float a = fabsf(s), ex = __expf(-2.f * a);
        hv[j] = copysignf((1.f - ex) / (1.f + ex), s);
      }
      #pragma unroll
      for (int j = 0; j < 4; j++){
        float s = s1[j] + (float)xpc[4 + j];
        float a = fabsf(s), ex = __expf(-2.f * a);
        hv[4 + j] = copysignf((1.f - ex) / (1.f + ex), s);
      }

      if (t < T_ - 1){
        union { _Float16 h[4]; u64 q; } g0, g1;
        #pragma unroll
        for (int j = 0; j < 4; j++){ g0.h[j] = (_Float16)hv[j]; g1.h[j] = (_Float16)hv[4 + j]; }
        _Float16* hn = hring + (long)((t + 1) & (RING - 1)) * BH;
        st_agent_u64((u64*)(hn + pubOff), g0.q);
        st_agent_u64((u64*)(hn + pubOff + 4), g1.q);
        if (t + 8 < T_){
          _Float16* hs = hring + (long)((t + 8) & (RING - 1)) * BH;
          st_agent_u64((u64*)(hs + pubOff), 0xFFFFFFFFFFFFFFFFull);
          st_agent_u64((u64*)(hs + pubOff + 4), 0xFFFFFFFFFFFFFFFFull);
        }
      } else {
        *(float4*)(hT + pubOff)     = make_float4(hv[0], hv[1], hv[2], hv[3]);
        *(float4*)(hT + pubOff + 4) = make_float4(hv[4], hv[5], hv[6], hv[7]);
      }
    }
    xpc = xpn;
  }
}

// ---------------------------------------------------------------------------
// Head: y1 = relu(hT @ fc1_w^T + b1);  out = y1 @ fc2_w^T + b2   (all fp32)
// ---------------------------------------------------------------------------
__global__ void fc1_kernel(const float* __restrict__ hT, const float* __restrict__ w1,
                           const float* __restrict__ b1, float* __restrict__ y1)
{
  int o = blockIdx.x * 256 + threadIdx.x;     // 0..65535
  int b = o >> 10, j = o & 1023;
  const float4* hp = (const float4*)(hT + (long)b * H_);
  const float4* wp = (const float4*)(w1 + (long)j * H_);
  float s = 0.f;
  #pragma unroll 4
  for (int k = 0; k < H_ / 4; k++){
    float4 hv = hp[k], wv = wp[k];
    s += hv.x * wv.x + hv.y * wv.y + hv.z * wv.z + hv.w * wv.w;
  }
  s += b1[j];
  y1[o] = s > 0.f ? s : 0.f;
}

__global__ void fc2_kernel(const float* __restrict__ y1, const float* __restrict__ w2,
                           const float* __restrict__ b2, float* __restrict__ out)
{
  __shared__ float ybuf[H_];
  int b = blockIdx.x;
  for (int k = threadIdx.x; k < H_; k += 256) ybuf[k] = y1[(long)b * H_ + k];
  __syncthreads();
  if (threadIdx.x < C_){
    const float* wp = w2 + (long)threadIdx.x * H_;
    float s = 0.f;
    for (int k = 0; k < H_; k++) s += ybuf[k] * wp[k];
    out[b * C_ + threadIdx.x] = s + b2[threadIdx.x];
  }
}

// ---------------------------------------------------------------------------
extern "C" void kernel_launch(void* const* d_in, const int* in_sizes, int n_in,
                              void* d_out, int out_size, void* d_ws, size_t ws_size,
                              hipStream_t stream)
{
  const float* x   = (const float*)d_in[0];
  const float* wih = (const float*)d_in[1];
  const float* whh = (const float*)d_in[2];
  const float* bih = (const float*)d_in[3];
  const float* bhh = (const float*)d_in[4];
  const float* w1  = (const float*)d_in[5];
  const float* b1  = (const float*)d_in[6];
  const float* w2  = (const float*)d_in[7];
  const float* b2  = (const float*)d_in[8];
  float* out = (float*)d_out;

  char* ws = (char*)d_ws;
  size_t off = 0;
  auto carve = [&](size_t bytes) -> char* {
    char* p = ws + off; off += (bytes + 255) & ~(size_t)255; return p;
  };
  _Float16* whhF  = (_Float16*)carve((size_t)H_ * H_ * 2);
  _Float16* wihF  = (_Float16*)carve((size_t)H_ * E_ * 2);
  _Float16* hring = (_Float16*)carve((size_t)RING * BH * 2);
  float*    hT    = (float*)carve((size_t)B_ * H_ * 4);
  float*    y1    = (float*)carve((size_t)B_ * H_ * 4);
  _Float16* xp    = (_Float16*)carve((size_t)T_ * BH * 2);   // 64 MB, plain

  prep_kernel<<<1024, 256, 0, stream>>>(wih, whh, whhF, wihF, (short*)hring);
  xp_gemm<<<512, 256, 0, stream>>>(x, wihF, bih, bhh, xp);
  rnn_scan<<<32, 256, 0, stream>>>(xp, whhF, hring, hT);
  fc1_kernel<<<256, 256, 0, stream>>>(hT, w1, b1, y1);
  fc2_kernel<<<64, 256, 0, stream>>>(y1, w2, b2, out);
}

// Round 12
// 1576.755 us; speedup vs baseline: 2.1403x; 1.3460x over previous
//
#include <hip/hip_runtime.h>

#define B_ 64
#define T_ 512
#define E_ 512
#define H_ 1024
#define C_ 20
#define RING 16
#define BH (B_ * H_)

typedef __attribute__((ext_vector_type(8))) _Float16 f16x8;
typedef __attribute__((ext_vector_type(4))) float f32x4;
typedef __attribute__((ext_vector_type(4))) unsigned int u32x4;
typedef unsigned long long u64;

__device__ __forceinline__ void st_agent_u64(u64* p, u64 v){
  __hip_atomic_store(p, v, __ATOMIC_RELAXED, __HIP_MEMORY_SCOPE_AGENT);
}
// Coherent 16B load (bypasses L1/L2, reads the device-coherent point).
// Caller must s_waitcnt vmcnt(0) + sched_barrier(0) before consuming.
__device__ __forceinline__ u32x4 ld_b128_cohere(const void* p){
  u32x4 r;
  asm volatile("global_load_dwordx4 %0, %1, off sc0 sc1"
               : "=v"(r) : "v"(p) : "memory");
  return r;
}

// ---------------------------------------------------------------------------
// Prep: W_hh/W_ih -> fp16, init h-ring (slot0 = h0 = zeros, slots 1..15 =
// 0xFFFF sentinel = fp16 NaN, never produced by tanh). Ring MUST be re-inited
// every launch (ws not re-poisoned between graph replays).
// ---------------------------------------------------------------------------
__global__ void prep_kernel(const float* __restrict__ wih,
                            const float* __restrict__ whh,
                            _Float16* __restrict__ whhF,
                            _Float16* __restrict__ wihF,
                            short* __restrict__ hring)
{
  const long NH = (long)H_ * H_;
  const long NI = (long)H_ * E_;
  const long NR = (long)RING * BH;
  const long TOT = NH + NI + NR;
  long i = (long)blockIdx.x * blockDim.x + threadIdx.x;
  const long stride = (long)gridDim.x * blockDim.x;
  for (; i < TOT; i += stride){
    if (i < NH){
      whhF[i] = (_Float16)whh[i];
    } else if (i < NH + NI){
      long j = i - NH;
      wihF[j] = (_Float16)wih[j];
    } else {
      long j = i - NH - NI;
      hring[j] = (j < BH) ? (short)0 : (short)0xFFFF;
    }
  }
}

// ---------------------------------------------------------------------------
// xp_gemm: xp[t][b][h] = x[b][t][:] @ W_ih[h][:] + b_ih[h] + b_hh[h], fp16,
// stored PLAIN [t][b][h] (the scan adds xp at the reducer stage: 4 contiguous
// fp16 = one 8B read per thread).
// ---------------------------------------------------------------------------
__global__ __launch_bounds__(256, 1) void xp_gemm(
    const float* __restrict__ x, const _Float16* __restrict__ wihF,
    const float* __restrict__ bih, const float* __restrict__ bhh,
    _Float16* __restrict__ xp)
{
  const int lane = threadIdx.x & 63;
  const int wv   = threadIdx.x >> 6;       // 0..3 -> col quarter
  const int bg   = blockIdx.x & 3;
  const int tb   = (blockIdx.x >> 2) * 4;  // 4 timesteps per block
  const int r16  = lane & 15;
  const int k8   = (lane >> 4) * 8;

  const int brow = bg * 16 + r16;

  f32x4 acc[4][16];
  #pragma unroll
  for (int t = 0; t < 4; t++)
    #pragma unroll
    for (int c = 0; c < 16; c++) acc[t][c] = { 0.f, 0.f, 0.f, 0.f };

  for (int kc = 0; kc < 16; kc++){
    f16x8 a[4];
    #pragma unroll
    for (int t = 0; t < 4; t++){
      const float* xp8 = x + ((long)brow * T_ + tb + t) * E_ + kc * 32 + k8;
      float4 f0 = *(const float4*)xp8;
      float4 f1 = *(const float4*)(xp8 + 4);
      f16x8 v;
      v[0]=(_Float16)f0.x; v[1]=(_Float16)f0.y; v[2]=(_Float16)f0.z; v[3]=(_Float16)f0.w;
      v[4]=(_Float16)f1.x; v[5]=(_Float16)f1.y; v[6]=(_Float16)f1.z; v[7]=(_Float16)f1.w;
      a[t] = v;
    }
    #pragma unroll
    for (int c = 0; c < 16; c++){
      f16x8 b = *(const f16x8*)(wihF + (long)(wv * 256 + c * 16 + r16) * E_ + kc * 32 + k8);
      #pragma unroll
      for (int t = 0; t < 4; t++)
        acc[t][c] = __builtin_amdgcn_mfma_f32_16x16x32_f16(a[t], b, acc[t][c], 0, 0, 0);
    }
  }
  // C-frag: col = wv*256 + c*16 + (lane&15); row = bg*16 + (lane>>4)*4 + j
  #pragma unroll
  for (int c = 0; c < 16; c++){
    int col = wv * 256 + c * 16 + r16;
    float bs = bih[col] + bhh[col];
    #pragma unroll
    for (int t = 0; t < 4; t++){
      #pragma unroll
      for (int j = 0; j < 4; j++){
        int row = bg * 16 + (lane >> 4) * 4 + j;
        xp[((long)(tb + t)) * BH + (long)row * H_ + col] =
            (_Float16)(acc[t][c][j] + bs);
      }
    }
  }
}

// ---------------------------------------------------------------------------
// Persistent scan v8: 32 blocks (4 bg x 8 cg) x 512 threads (8 waves).
// Block owns [16 batch rows x 128 cols]; K=1024 split over 8 waves (128 K
// each). Wave w's K-slice lies entirely inside producer block (bg, cg'=w):
// FAN-IN 1 PER WAVE, poll payload 4 KB/wave (4 x 16B per lane). Weights:
// 128 cols x 128 K fp16 = 32 KB/wave = 128 VGPRs, pinned.
//
// Per-step pipeline discipline:
//  - poll loads are the ONLY vmem in flight during the poll (vmcnt(0) per
//    round is cheap);
//  - xp(t+1) prefetch (one 8B cached load) is issued immediately AFTER the
//    poll loop exits -> ~0.5-0.7 us of flight before the next vmcnt(0)
//    drain, HBM latency fully hidden; consumed at the next reducer stage.
//  - partials in one 66 KB LDS buffer; two lgkm-only barriers (write->reduce,
//    and read->next-write WAR); publish BEFORE barrier-2 for earliest
//    producer visibility.
// Exchange protocol (proven R4-R11): 16-slot sentinel ring, 8B single-copy-
// atomic granules, 0xFFFF fp16-NaN sentinel, re-sentinel slot t+8,
// arrival-order fused MFMAs, relaxed agent ops only.
// ---------------------------------------------------------------------------
__global__ __launch_bounds__(512, 1) void rnn_scan(
    const _Float16* __restrict__ xp, const _Float16* __restrict__ whhF,
    _Float16* __restrict__ hring, float* __restrict__ hT)
{
  const int tid  = threadIdx.x;
  const int lane = tid & 63;
  const int w    = tid >> 6;          // wave 0..7: K-slice == producer cg'
  const int bg   = blockIdx.x & 3;    // batch group (16 rows)
  const int cg   = blockIdx.x >> 2;   // col group 0..7 (128 cols)
  const int r16  = lane & 15;
  const int kq   = lane >> 4;         // 0..3

  __shared__ float part[8][16][132];  // [wave][row][col(+pad)] = 66 KB

  // --- pinned W_hh fragments: [col-tile ct 0..7][K-chunk kc 0..3] ---
  f16x8 wh[8][4];
  #pragma unroll
  for (int ct = 0; ct < 8; ct++)
    #pragma unroll
    for (int kc = 0; kc < 4; kc++)
      wh[ct][kc] = *(const f16x8*)(whhF +
          (long)(cg * 128 + ct * 16 + r16) * H_ + w * 128 + kc * 32 + kq * 8);
  #pragma unroll
  for (int ct = 0; ct < 8; ct++)
    #pragma unroll
    for (int kc = 0; kc < 4; kc++)
      asm volatile("" : "+v"(wh[ct][kc]));

  // consumer A-frag base: row = bg*16 + r16, K = w*128 + kc*32 + kq*8
  const long haOff = (long)(bg * 16 + r16) * H_ + w * 128 + kq * 8;
  // reducer/publisher mapping: thread -> (row rr, col-quad cc4)
  const int  rr  = tid >> 5;          // 0..15
  const int  cc4 = tid & 31;          // 0..31 (4 cols each)
  const long pubOff = (long)(bg * 16 + rr) * H_ + cg * 128 + cc4 * 4;

  union { _Float16 h[4]; u64 q; } xc, xn;
  xc.q = *(const u64*)(xp + pubOff);  // xp(0)
  xn.q = 0;

  for (int t = 0; t < T_; ++t){
    // ---- poll h(t): 4 x 16B coherent loads from ONE producer ----
    const _Float16* hb = hring + (long)(t & (RING - 1)) * BH + haOff;
    u32x4 q[4];
    #pragma unroll
    for (int c = 0; c < 4; c++) q[c] = ld_b128_cohere(hb + c * 32);
    asm volatile("s_waitcnt vmcnt(0)" ::: "memory");
    __builtin_amdgcn_sched_barrier(0);

    f32x4 acc[8];
    #pragma unroll
    for (int ct = 0; ct < 8; ct++) acc[ct] = { 0.f, 0.f, 0.f, 0.f };

    unsigned need = 0xFu;
    while (true){
      #pragma unroll
      for (int c = 0; c < 4; c++){
        if (need & (1u << c)){
          bool bad = ((q[c][0] & 0xFFFFu) == 0xFFFFu) ||
                     ((q[c][2] & 0xFFFFu) == 0xFFFFu);
          if (!__any(bad)){
            union { u32x4 u; f16x8 v; } hu; hu.u = q[c];
            #pragma unroll
            for (int ct = 0; ct < 8; ct++)
              acc[ct] = __builtin_amdgcn_mfma_f32_16x16x32_f16(hu.v, wh[ct][c], acc[ct], 0, 0, 0);
            need &= ~(1u << c);
          }
        }
      }
      if (!need) break;
      #pragma unroll
      for (int c = 0; c < 4; c++)
        if (need & (1u << c)) q[c] = ld_b128_cohere(hb + c * 32);
      asm volatile("s_waitcnt vmcnt(0)" ::: "memory");
      __builtin_amdgcn_sched_barrier(0);
    }

    // ---- xp prefetch for t+1: issued EARLY (max flight before next drain) ----
    if (t + 1 < T_)
      xn.q = *(const u64*)(xp + (long)(t + 1) * BH + pubOff);

    // ---- partials to LDS; barrier 1 (lgkm-only) ----
    #pragma unroll
    for (int ct = 0; ct < 8; ct++)
      #pragma unroll
      for (int j = 0; j < 4; j++)
        part[w][kq * 4 + j][ct * 16 + r16] = acc[ct][j];
    asm volatile("s_waitcnt lgkmcnt(0)\n\ts_barrier" ::: "memory");

    // ---- reduce 8 waves' partials + xp, tanh, publish ----
    {
      f32x4 s = *(const f32x4*)&part[0][rr][cc4 * 4];
      #pragma unroll
      for (int p = 1; p < 8; p++)
        s += *(const f32x4*)&part[p][rr][cc4 * 4];
      float hv[4];
      #pragma unroll
      for (int j = 0; j < 4; j++){
        float v = s[j] + (float)xc.h[j];
        float a = fabsf(v), ex = __expf(-2.f * a);
        hv[j] = copysignf((1.f - ex) / (1.f + ex), v);
      }

      if (t < T_ - 1){
        union { _Float16 h[4]; u64 q; } g;
        #pragma unroll
        for (int j = 0; j < 4; j++) g.h[j] = (_Float16)hv[j];
        st_agent_u64((u64*)(hring + (long)((t + 1) & (RING - 1)) * BH + pubOff), g.q);
        if (t + 8 < T_)
          st_agent_u64((u64*)(hring + (long)((t + 8) & (RING - 1)) * BH + pubOff),
                       0xFFFFFFFFFFFFFFFFull);
      } else {
        *(float4*)(hT + pubOff) = make_float4(hv[0], hv[1], hv[2], hv[3]);
      }
    }
    // ---- barrier 2: protect this step's LDS reads from next step's writes ----
    asm volatile("s_waitcnt lgkmcnt(0)\n\ts_barrier" ::: "memory");
    xc.q = xn.q;
  }
}

// ---------------------------------------------------------------------------
// Head: y1 = relu(hT @ fc1_w^T + b1);  out = y1 @ fc2_w^T + b2   (all fp32)
// ---------------------------------------------------------------------------
__global__ void fc1_kernel(const float* __restrict__ hT, const float* __restrict__ w1,
                           const float* __restrict__ b1, float* __restrict__ y1)
{
  int o = blockIdx.x * 256 + threadIdx.x;     // 0..65535
  int b = o >> 10, j = o & 1023;
  const float4* hp = (const float4*)(hT + (long)b * H_);
  const float4* wp = (const float4*)(w1 + (long)j * H_);
  float s = 0.f;
  #pragma unroll 4
  for (int k = 0; k < H_ / 4; k++){
    float4 hv = hp[k], wv = wp[k];
    s += hv.x * wv.x + hv.y * wv.y + hv.z * wv.z + hv.w * wv.w;
  }
  s += b1[j];
  y1[o] = s > 0.f ? s : 0.f;
}

__global__ void fc2_kernel(const float* __restrict__ y1, const float* __restrict__ w2,
                           const float* __restrict__ b2, float* __restrict__ out)
{
  __shared__ float ybuf[H_];
  int b = blockIdx.x;
  for (int k = threadIdx.x; k < H_; k += 256) ybuf[k] = y1[(long)b * H_ + k];
  __syncthreads();
  if (threadIdx.x < C_){
    const float* wp = w2 + (long)threadIdx.x * H_;
    float s = 0.f;
    for (int k = 0; k < H_; k++) s += ybuf[k] * wp[k];
    out[b * C_ + threadIdx.x] = s + b2[threadIdx.x];
  }
}

// ---------------------------------------------------------------------------
extern "C" void kernel_launch(void* const* d_in, const int* in_sizes, int n_in,
                              void* d_out, int out_size, void* d_ws, size_t ws_size,
                              hipStream_t stream)
{
  const float* x   = (const float*)d_in[0];
  const float* wih = (const float*)d_in[1];
  const float* whh = (const float*)d_in[2];
  const float* bih = (const float*)d_in[3];
  const float* bhh = (const float*)d_in[4];
  const float* w1  = (const float*)d_in[5];
  const float* b1  = (const float*)d_in[6];
  const float* w2  = (const float*)d_in[7];
  const float* b2  = (const float*)d_in[8];
  float* out = (float*)d_out;

  char* ws = (char*)d_ws;
  size_t off = 0;
  auto carve = [&](size_t bytes) -> char* {
    char* p = ws + off; off += (bytes + 255) & ~(size_t)255; return p;
  };
  _Float16* whhF  = (_Float16*)carve((size_t)H_ * H_ * 2);
  _Float16* wihF  = (_Float16*)carve((size_t)H_ * E_ * 2);
  _Float16* hring = (_Float16*)carve((size_t)RING * BH * 2);
  float*    hT    = (float*)carve((size_t)B_ * H_ * 4);
  float*    y1    = (float*)carve((size_t)B_ * H_ * 4);
  _Float16* xp    = (_Float16*)carve((size_t)T_ * BH * 2);   // 64 MB, plain

  prep_kernel<<<1024, 256, 0, stream>>>(wih, whh, whhF, wihF, (short*)hring);
  xp_gemm<<<512, 256, 0, stream>>>(x, wihF, bih, bhh, xp);
  rnn_scan<<<32, 512, 0, stream>>>(xp, whhF, hring, hT);
  fc1_kernel<<<256, 256, 0, stream>>>(hT, w1, b1, y1);
  fc2_kernel<<<64, 256, 0, stream>>>(y1, w2, b2, out);
}